// Round 18
// baseline (104.860 us; speedup 1.0000x reference)
//
#include <hip/hip_runtime.h>
#include <hip/hip_bf16.h>

#define L2E 1.4426950408889634f
#define BNF 0.99999500003749969f   // 1/sqrt(1+1e-5)

typedef __attribute__((ext_vector_type(4))) float f4;
typedef __attribute__((ext_vector_type(4))) float f32x4;
typedef __attribute__((ext_vector_type(4))) int i4;
typedef __attribute__((ext_vector_type(8))) short bfrag;   // 8 bf16 = 4 VGPRs

__device__ __forceinline__ int cvtpk(float lo, float hi) {
  int r;
  asm("v_cvt_pk_bf16_f32 %0, %1, %2" : "=v"(r) : "v"(lo), "v"(hi));
  return r;
}

#define MFMA16(a, b, c) __builtin_amdgcn_mfma_f32_16x16x32_bf16(a, b, c, 0, 0, 0)

// ======= prep1: pack_adj [0,2048) | conv_frag [2048,2880) | wa [2880,2896) =======
__global__ __launch_bounds__(256) void prep1(
    const float* __restrict__ c_feat, const float* __restrict__ d_feat,
    const float* __restrict__ c_W, const float* __restrict__ d_W,
    const float* __restrict__ c_a, const float* __restrict__ d_a,
    const int* __restrict__ adj,
    unsigned* __restrict__ adjP, unsigned* __restrict__ adjPT,
    unsigned short* __restrict__ Xb_c, unsigned short* __restrict__ Xb_d,
    unsigned short* __restrict__ Wb_c, unsigned short* __restrict__ Wb_d,
    float* __restrict__ wa_c, float* __restrict__ wa_d) {
  const int b = blockIdx.x;
  const int t = threadIdx.x;
  if (b < 2048) {
    // ---- pack_adj (fragment-major bitmasks) ----
    __shared__ int s[64][65];
    const int m0 = (b & 31) * 64, n0 = (b >> 5) * 64;
#pragma unroll
    for (int i = 0; i < 4; ++i) {
      int idx = t + i * 256;
      int r = idx >> 4, c4 = (idx & 15) * 4;
      i4 v = __builtin_nontemporal_load(
          (const i4*)(adj + (size_t)(n0 + r) * 2048 + m0 + c4));
      s[r][c4 + 0] = v.x; s[r][c4 + 1] = v.y;
      s[r][c4 + 2] = v.z; s[r][c4 + 3] = v.w;
    }
    __syncthreads();
    const int w = t >> 6, l = t & 63;
#pragma unroll 4
    for (int rr = 0; rr < 16; ++rr) {
      int r = w * 16 + rr;
      int n = n0 + r;
      unsigned long long bb = __ballot(s[r][l] != 0);
      if (l == 0) {
        size_t base = ((size_t)(n >> 4) * 64 + (m0 >> 5)) * 16 + (n & 15);
        adjP[base] = (unsigned)bb;
        adjP[base + 16] = (unsigned)(bb >> 32);
      }
    }
#pragma unroll 4
    for (int cc = 0; cc < 16; ++cc) {
      int m = m0 + w * 16 + cc;
      unsigned long long bb = __ballot(s[l][w * 16 + cc] != 0);
      if (l == 0) {
        size_t base = ((size_t)(m >> 4) * 128 + (n0 >> 5)) * 16 + (m & 15);
        adjPT[base] = (unsigned)bb;
        adjPT[base + 16] = (unsigned)(bb >> 32);
      }
    }
  } else if (b < 2880) {
    // ---- conv_frag: X/W -> MFMA fragment-major bf16 ----
    int idx = (b - 2048) * 256 + t;   // < 212992
    const float* S; unsigned short* D; int tt;
    if (idx < 65536)       { S = d_feat; D = Xb_c; tt = idx; }
    else if (idx < 196608) { S = c_feat; D = Xb_d; tt = idx - 65536; }
    else if (idx < 204800) { S = c_W;    D = Wb_c; tt = idx - 196608; }
    else                   { S = d_W;    D = Wb_d; tt = idx - 204800; }
    int l = tt & 63, kt = (tt >> 6) & 7, tile = tt >> 9;
    int row = tile * 16 + (l & 15);
    int col = kt * 32 + (l >> 4) * 8;
    const float* sp = S + (size_t)row * 256 + col;
    f4 v0 = *(const f4*)sp;
    f4 v1 = *(const f4*)(sp + 4);
    uint4 u;
    u.x = (unsigned)cvtpk(v0.x, v0.y);
    u.y = (unsigned)cvtpk(v0.z, v0.w);
    u.z = (unsigned)cvtpk(v1.x, v1.y);
    u.w = (unsigned)cvtpk(v1.z, v1.w);
    *(uint4*)(D + (size_t)tt * 8) = u;
  } else {
    // ---- wa[h][k] = L2E * sum_d a[h*64+d] * W[(h*32+d)*256+k] ----
    int idx = (b - 2880) * 256 + t;   // < 4096
    bool cs = idx < 2048;
    int i2 = idx & 2047;
    int h = i2 >> 8, k = i2 & 255;
    const float* W = cs ? c_W : d_W;
    const float* a = cs ? c_a : d_a;
    float s = 0.f;
#pragma unroll 8
    for (int d = 0; d < 32; ++d)
      s = fmaf(a[h * 64 + d], W[(size_t)(h * 32 + d) * 256 + k], s);
    (cs ? wa_c : wa_d)[i2] = s * L2E;
  }
}

// ======= gemm2: MFMA GEMM [0,768) | et dots [768,1536), 64 threads =======
__global__ __launch_bounds__(64) void gemm2(
    const unsigned short* __restrict__ Xb_c, const unsigned short* __restrict__ Wb_c,
    const unsigned short* __restrict__ Xb_d, const unsigned short* __restrict__ Wb_d,
    const float* __restrict__ c_a, const float* __restrict__ d_a,
    unsigned short* __restrict__ Sbt_c, unsigned short* __restrict__ Sbt_d,
    float* __restrict__ es2t_c, float* __restrict__ es2t_d,
    const float* __restrict__ c_feat, const float* __restrict__ d_feat,
    const float* __restrict__ wa_c, const float* __restrict__ wa_d,
    float* __restrict__ et2_c, float* __restrict__ et2_d) {
  const int b = blockIdx.x;
  if (b < 768) {
    const bool cs = b < 256;
    const int bb = cs ? b : b - 256;
    const int rt = bb >> 1, half = bb & 1;
    const unsigned short* Xb = cs ? Xb_c : Xb_d;
    const unsigned short* Wb = cs ? Wb_c : Wb_d;
    const float* av = cs ? c_a : d_a;
    unsigned short* Sbt = cs ? Sbt_c : Sbt_d;
    float* es2t = cs ? es2t_c : es2t_d;
    const int Mrows = cs ? 2048 : 4096;
    const int l = threadIdx.x;
    const int g = l >> 4, c16 = l & 15;
    bfrag afr[8];
#pragma unroll
    for (int kt = 0; kt < 8; ++kt)
      afr[kt] = *(const bfrag*)(Xb + ((size_t)(rt * 8 + kt) * 64 + l) * 8);
    float esacc[4] = {};
#pragma unroll
    for (int c8 = 0; c8 < 8; ++c8) {
      const int cht = half * 8 + c8;
      f32x4 acc = {0.f, 0.f, 0.f, 0.f};
#pragma unroll
      for (int kt = 0; kt < 8; ++kt) {
        bfrag wfr = *(const bfrag*)(Wb + ((size_t)(cht * 8 + kt) * 64 + l) * 8);
        acc = MFMA16(afr[kt], wfr, acc);
      }
      const int mtb = rt * 2 + (g >> 1);
      size_t soff = (((size_t)cht * (Mrows >> 3) + mtb) * 16 + c16) * 8 + (g & 1) * 4;
      uint2 u;
      u.x = (unsigned)cvtpk(acc[0], acc[1]);
      u.y = (unsigned)cvtpk(acc[2], acc[3]);
      *(uint2*)(Sbt + soff) = u;
      const int h = cht >> 1, sub = cht & 1;
      const float aw = av[h * 64 + 32 + sub * 16 + c16];
      if (sub == 0) {
#pragma unroll
        for (int i = 0; i < 4; ++i) esacc[i] = acc[i] * aw;
      } else {
#pragma unroll
        for (int i = 0; i < 4; ++i) esacc[i] = fmaf(acc[i], aw, esacc[i]);
#pragma unroll
        for (int i = 0; i < 4; ++i) {
          esacc[i] += __shfl_xor(esacc[i], 1);
          esacc[i] += __shfl_xor(esacc[i], 2);
          esacc[i] += __shfl_xor(esacc[i], 4);
          esacc[i] += __shfl_xor(esacc[i], 8);
        }
        if (c16 == 0) {
          f4 o = {esacc[0] * L2E, esacc[1] * L2E, esacc[2] * L2E, esacc[3] * L2E};
          *(f4*)(es2t + (size_t)h * Mrows + rt * 16 + g * 4) = o;
        }
      }
    }
  } else {
    int idx = (b - 768) * 64 + threadIdx.x;   // < 49152
    bool cs = idx < 32768;
    int i2 = cs ? idx : idx - 32768;
    const float* X = cs ? c_feat : d_feat;
    const float* wa = cs ? wa_c : wa_d;
    float* et2 = cs ? et2_c : et2_d;
    int r = i2 >> 3, h = i2 & 7;
    const float* xp = X + (size_t)r * 256;
    const float* ap = wa + h * 256;
    float s = 0.f;
#pragma unroll 16
    for (int k = 0; k < 256; k += 4) {
      f4 xv = *(const f4*)(xp + k);
      f4 av = *(const f4*)(ap + k);
      s = fmaf(xv.x, av.x, s); s = fmaf(xv.y, av.y, s);
      s = fmaf(xv.z, av.z, s); s = fmaf(xv.w, av.w, s);
    }
    et2[i2] = s;
  }
}

// ------- P-gen (exp2, masked AFTER exp2) -------
__device__ __forceinline__ bfrag make_pfrag2(float et, f4 e0, f4 e1,
                                             unsigned bits) {
  float xv[8] = {e0.x, e0.y, e0.z, e0.w, e1.x, e1.y, e1.z, e1.w};
  float p[8];
#pragma unroll
  for (int e = 0; e < 8; ++e) {
    float x = et + xv[e];
    x = fmaxf(x, 0.2f * x);                 // LeakyReLU (exp2 domain)
    float pe = __builtin_amdgcn_exp2f(x);
    p[e] = ((bits >> e) & 1u) ? pe : 0.f;
  }
  union { bfrag v; int i[4]; } u;
#pragma unroll
  for (int e = 0; e < 4; ++e) u.i[e] = cvtpk(p[2 * e], p[2 * e + 1]);
  return u.v;
}

// ======= fused_rs: row/head-split, waves split M, in-block reduction, direct out ======
// c-side: b in [0,1024): hp=b&3, tile=b>>2 (256 tiles). d-side: b-1024, 128 tiles.
__global__ __launch_bounds__(256) void fused_rs(
    const float* __restrict__ et2_c, const float* __restrict__ es2t_c,
    const unsigned* __restrict__ adjP, const unsigned short* __restrict__ Sbt_c,
    const float* __restrict__ et2_d, const float* __restrict__ es2t_d,
    const unsigned* __restrict__ adjPT, const unsigned short* __restrict__ Sbt_d,
    float* __restrict__ out,
    const float* __restrict__ gc, const float* __restrict__ bc,
    const float* __restrict__ gd, const float* __restrict__ bd) {
  __shared__ __align__(16) f4 red[4][6][64];   // 24 KB
  const int b = blockIdx.x;
  const bool cs = b < 1024;
  const int bb = cs ? b : b - 1024;
  const int hp = bb & 3, tile = bb >> 2;
  const int n0 = tile * 16;
  const int M = cs ? 2048 : 4096;
  const float* et2 = cs ? et2_c : et2_d;
  const float* es2t = cs ? es2t_c : es2t_d;
  const unsigned* adjPk = cs ? adjP : adjPT;
  const unsigned short* Sbt = cs ? Sbt_c : Sbt_d;
  const float* bng = cs ? gc : gd;
  const float* bnb = cs ? bc : bd;
  float* outp = cs ? out : out + (size_t)4096 * 256;

  const int Mw = M >> 5;
  const int Mq = M >> 2;                        // per-wave m span
  const int tid = threadIdx.x;
  const int w = tid >> 6, l = tid & 63;
  const int g = l >> 4, c16 = l & 15;
  const int hA = hp * 2, hB = hp * 2 + 1;
  const int row = n0 + c16;
  const float etA = et2[row * 8 + hA];
  const float etB = et2[row * 8 + hB];
  const int Mt16 = M * 16;
  const int lane_off = g * 128 + c16 * 8;
  const unsigned short* pA0 = Sbt + (size_t)(hA * 2) * Mt16 + lane_off;
  const unsigned short* pA1 = pA0 + Mt16;
  const unsigned short* pB0 = Sbt + (size_t)(hB * 2) * Mt16 + lane_off;
  const unsigned short* pB1 = pB0 + Mt16;
  const unsigned* adjt = adjPk + (size_t)tile * Mw * 16 + c16;
  const float* esArow = es2t + (size_t)hA * M;
  const float* esBrow = es2t + (size_t)hB * M;
  f32x4 accA0 = {0.f, 0.f, 0.f, 0.f}, accA1 = accA0, denA = accA0;
  f32x4 accB0 = accA0, accB1 = accA0, denB = accA0;
  union { bfrag v; int i[4]; } uo;
#pragma unroll
  for (int e = 0; e < 4; ++e) uo.i[e] = 0x3F803F80;   // bf16(1.0) pairs
  const bfrag ones = uo.v;

  auto body = [&](int m0) {
    const unsigned w0 = adjt[(m0 >> 5) * 16];
    const unsigned w1 = adjt[(m0 >> 5) * 16 + 16];
    const int moa = m0 + g * 8;
    const int i8 = (m0 >> 3) * 128;
    f4 eA0 = *(const f4*)(esArow + moa);
    f4 eA1 = *(const f4*)(esArow + moa + 4);
    f4 eB0 = *(const f4*)(esBrow + moa);
    f4 eB1 = *(const f4*)(esBrow + moa + 4);
    f4 fA0 = *(const f4*)(esArow + moa + 32);
    f4 fA1 = *(const f4*)(esArow + moa + 36);
    f4 fB0 = *(const f4*)(esBrow + moa + 32);
    f4 fB1 = *(const f4*)(esBrow + moa + 36);
    bfrag bA0a = *(const bfrag*)(pA0 + i8);
    bfrag bA1a = *(const bfrag*)(pA1 + i8);
    bfrag bB0a = *(const bfrag*)(pB0 + i8);
    bfrag bB1a = *(const bfrag*)(pB1 + i8);
    bfrag bA0b = *(const bfrag*)(pA0 + i8 + 512);
    bfrag bA1b = *(const bfrag*)(pA1 + i8 + 512);
    bfrag bB0b = *(const bfrag*)(pB0 + i8 + 512);
    bfrag bB1b = *(const bfrag*)(pB1 + i8 + 512);
    const unsigned bits0 = (w0 >> (g * 8)) & 0xffu;
    const unsigned bits1 = (w1 >> (g * 8)) & 0xffu;
    bfrag aA = make_pfrag2(etA, eA0, eA1, bits0);
    bfrag aB = make_pfrag2(etB, eB0, eB1, bits0);
    accA0 = MFMA16(aA, bA0a, accA0);
    accA1 = MFMA16(aA, bA1a, accA1);
    denA  = MFMA16(aA, ones, denA);
    accB0 = MFMA16(aB, bB0a, accB0);
    accB1 = MFMA16(aB, bB1a, accB1);
    denB  = MFMA16(aB, ones, denB);
    bfrag cA = make_pfrag2(etA, fA0, fA1, bits1);
    bfrag cB = make_pfrag2(etB, fB0, fB1, bits1);
    accA0 = MFMA16(cA, bA0b, accA0);
    accA1 = MFMA16(cA, bA1b, accA1);
    denA  = MFMA16(cA, ones, denA);
    accB0 = MFMA16(cB, bB0b, accB0);
    accB1 = MFMA16(cB, bB1b, accB1);
    denB  = MFMA16(cB, ones, denB);
  };

  const int mstart = w * Mq;
#pragma unroll 1
  for (int mm = 0; mm < Mq; mm += 512) {
#pragma unroll
    for (int it = 0; it < 8; ++it)
      body(mstart + mm + it * 64);
  }

  // cross-wave reduction: each wave deposits 6 f4; wave 0 sums and writes out.
  red[w][0][l] = accA0; red[w][1][l] = accA1; red[w][2][l] = denA;
  red[w][3][l] = accB0; red[w][4][l] = accB1; red[w][5][l] = denB;
  __syncthreads();
  if (w == 0) {
    f4 rA0 = red[0][0][l] + red[1][0][l] + red[2][0][l] + red[3][0][l];
    f4 rA1 = red[0][1][l] + red[1][1][l] + red[2][1][l] + red[3][1][l];
    f4 rdA = red[0][2][l] + red[1][2][l] + red[2][2][l] + red[3][2][l];
    f4 rB0 = red[0][3][l] + red[1][3][l] + red[2][3][l] + red[3][3][l];
    f4 rB1 = red[0][4][l] + red[1][4][l] + red[2][4][l] + red[3][4][l];
    f4 rdB = red[0][5][l] + red[1][5][l] + red[2][5][l] + red[3][5][l];
#define EPILOGUE(acc0, acc1, den, h)                                          \
    {                                                                         \
      const int c0 = (h) * 32 + c16, c1 = (h) * 32 + 16 + c16;                \
      const float g0 = bng[c0] * BNF, b0 = bnb[c0];                           \
      const float g1 = bng[c1] * BNF, b1 = bnb[c1];                           \
      _Pragma("unroll") for (int i = 0; i < 4; ++i) {                         \
        float rs = 1.f / fmaxf(den[i], 1e-30f);                               \
        float* op = outp + (size_t)(n0 + g * 4 + i) * 256;                    \
        op[c0] = fmaxf(fmaf(acc0[i] * rs, g0, b0), 0.f);                      \
        op[c1] = fmaxf(fmaf(acc1[i] * rs, g1, b1), 0.f);                      \
      }                                                                       \
    }
    EPILOGUE(rA0, rA1, rdA, hA)
    EPILOGUE(rB0, rB1, rdB, hB)
#undef EPILOGUE
  }
}

extern "C" void kernel_launch(void* const* d_in, const int* in_sizes, int n_in,
                              void* d_out, int out_size, void* d_ws, size_t ws_size,
                              hipStream_t stream) {
  const float* c_feat = (const float*)d_in[0];   // [4096,256]
  const float* d_feat = (const float*)d_in[1];   // [2048,256]
  const int*   adj    = (const int*)d_in[2];     // [4096,2048]
  const float* c_W    = (const float*)d_in[3];
  const float* c_a    = (const float*)d_in[4];   // [8,64]
  const float* d_W    = (const float*)d_in[5];
  const float* d_a    = (const float*)d_in[6];
  const float* c_bn_g = (const float*)d_in[7];
  const float* c_bn_b = (const float*)d_in[8];
  const float* d_bn_g = (const float*)d_in[9];
  const float* d_bn_b = (const float*)d_in[10];
  float* out = (float*)d_out;

  char* w = (char*)d_ws;
  size_t off = 0;
  auto take = [&](size_t bytes) -> char* {
    char* p = w + off;
    off += (bytes + 255) & ~(size_t)255;
    return p;
  };
  unsigned short* Sbt_c = (unsigned short*)take(256 * 2048 * 2);
  unsigned short* Sbt_d = (unsigned short*)take(256 * 4096 * 2);
  unsigned short* Xb_c  = (unsigned short*)take(2048 * 256 * 2);
  unsigned short* Xb_d  = (unsigned short*)take(4096 * 256 * 2);
  unsigned short* Wb_c  = (unsigned short*)take(256 * 256 * 2);
  unsigned short* Wb_d  = (unsigned short*)take(256 * 256 * 2);
  float* et2_c  = (float*)take(4096 * 8 * 4);
  float* es2t_c = (float*)take(8 * 2048 * 4);
  float* et2_d  = (float*)take(2048 * 8 * 4);
  float* es2t_d = (float*)take(8 * 4096 * 4);
  float* wa_c   = (float*)take(8 * 256 * 4);
  float* wa_d   = (float*)take(8 * 256 * 4);
  unsigned* adjP  = (unsigned*)take(4096 * 64 * 4);
  unsigned* adjPT = (unsigned*)take(2048 * 128 * 4);
  (void)off; (void)ws_size;

  dim3 blk(256);
  prep1<<<2896, blk, 0, stream>>>(c_feat, d_feat, c_W, d_W, c_a, d_a, adj,
                                  adjP, adjPT, Xb_c, Xb_d, Wb_c, Wb_d,
                                  wa_c, wa_d);
  gemm2<<<1536, dim3(64), 0, stream>>>(Xb_c, Wb_c, Xb_d, Wb_d, c_a, d_a,
                                       Sbt_c, Sbt_d, es2t_c, es2t_d,
                                       c_feat, d_feat, wa_c, wa_d,
                                       et2_c, et2_d);
  fused_rs<<<1536, blk, 0, stream>>>(et2_c, es2t_c, adjP, Sbt_c,
                                     et2_d, es2t_d, adjPT, Sbt_d,
                                     out, c_bn_g, c_bn_b, d_bn_g, d_bn_b);
}

// Round 19
// 73.755 us; speedup vs baseline: 1.4217x; 1.4217x over previous
//
#include <hip/hip_runtime.h>
#include <hip/hip_bf16.h>

#define L2E 1.4426950408889634f
#define BNF 0.99999500003749969f   // 1/sqrt(1+1e-5)

typedef __attribute__((ext_vector_type(4))) float f4;
typedef __attribute__((ext_vector_type(4))) float f32x4;
typedef __attribute__((ext_vector_type(4))) int i4;
typedef __attribute__((ext_vector_type(8))) short bfrag;   // 8 bf16 = 4 VGPRs

__device__ __forceinline__ int cvtpk(float lo, float hi) {
  int r;
  asm("v_cvt_pk_bf16_f32 %0, %1, %2" : "=v"(r) : "v"(lo), "v"(hi));
  return r;
}

#define MFMA16(a, b, c) __builtin_amdgcn_mfma_f32_16x16x32_bf16(a, b, c, 0, 0, 0)

// ======= prep1: pack_adj [0,2048) | conv_frag [2048,2880) | wa [2880,2896) =======
__global__ __launch_bounds__(256) void prep1(
    const float* __restrict__ c_feat, const float* __restrict__ d_feat,
    const float* __restrict__ c_W, const float* __restrict__ d_W,
    const float* __restrict__ c_a, const float* __restrict__ d_a,
    const int* __restrict__ adj,
    unsigned* __restrict__ adjP, unsigned* __restrict__ adjPT,
    unsigned short* __restrict__ Xb_c, unsigned short* __restrict__ Xb_d,
    unsigned short* __restrict__ Wb_c, unsigned short* __restrict__ Wb_d,
    float* __restrict__ wa_c, float* __restrict__ wa_d) {
  const int b = blockIdx.x;
  const int t = threadIdx.x;
  if (b < 2048) {
    // ---- pack_adj (fragment-major bitmasks) ----
    __shared__ int s[64][65];
    const int m0 = (b & 31) * 64, n0 = (b >> 5) * 64;
#pragma unroll
    for (int i = 0; i < 4; ++i) {
      int idx = t + i * 256;
      int r = idx >> 4, c4 = (idx & 15) * 4;
      i4 v = __builtin_nontemporal_load(
          (const i4*)(adj + (size_t)(n0 + r) * 2048 + m0 + c4));
      s[r][c4 + 0] = v.x; s[r][c4 + 1] = v.y;
      s[r][c4 + 2] = v.z; s[r][c4 + 3] = v.w;
    }
    __syncthreads();
    const int w = t >> 6, l = t & 63;
#pragma unroll 4
    for (int rr = 0; rr < 16; ++rr) {
      int r = w * 16 + rr;
      int n = n0 + r;
      unsigned long long bb = __ballot(s[r][l] != 0);
      if (l == 0) {
        size_t base = ((size_t)(n >> 4) * 64 + (m0 >> 5)) * 16 + (n & 15);
        adjP[base] = (unsigned)bb;
        adjP[base + 16] = (unsigned)(bb >> 32);
      }
    }
#pragma unroll 4
    for (int cc = 0; cc < 16; ++cc) {
      int m = m0 + w * 16 + cc;
      unsigned long long bb = __ballot(s[l][w * 16 + cc] != 0);
      if (l == 0) {
        size_t base = ((size_t)(m >> 4) * 128 + (n0 >> 5)) * 16 + (m & 15);
        adjPT[base] = (unsigned)bb;
        adjPT[base + 16] = (unsigned)(bb >> 32);
      }
    }
  } else if (b < 2880) {
    // ---- conv_frag: X/W -> MFMA fragment-major bf16 ----
    int idx = (b - 2048) * 256 + t;   // < 212992
    const float* S; unsigned short* D; int tt;
    if (idx < 65536)       { S = d_feat; D = Xb_c; tt = idx; }
    else if (idx < 196608) { S = c_feat; D = Xb_d; tt = idx - 65536; }
    else if (idx < 204800) { S = c_W;    D = Wb_c; tt = idx - 196608; }
    else                   { S = d_W;    D = Wb_d; tt = idx - 204800; }
    int l = tt & 63, kt = (tt >> 6) & 7, tile = tt >> 9;
    int row = tile * 16 + (l & 15);
    int col = kt * 32 + (l >> 4) * 8;
    const float* sp = S + (size_t)row * 256 + col;
    f4 v0 = *(const f4*)sp;
    f4 v1 = *(const f4*)(sp + 4);
    uint4 u;
    u.x = (unsigned)cvtpk(v0.x, v0.y);
    u.y = (unsigned)cvtpk(v0.z, v0.w);
    u.z = (unsigned)cvtpk(v1.x, v1.y);
    u.w = (unsigned)cvtpk(v1.z, v1.w);
    *(uint4*)(D + (size_t)tt * 8) = u;
  } else {
    // ---- wa[h][k] = L2E * sum_d a[h*64+d] * W[(h*32+d)*256+k] ----
    int idx = (b - 2880) * 256 + t;   // < 4096
    bool cs = idx < 2048;
    int i2 = idx & 2047;
    int h = i2 >> 8, k = i2 & 255;
    const float* W = cs ? c_W : d_W;
    const float* a = cs ? c_a : d_a;
    float s = 0.f;
#pragma unroll 8
    for (int d = 0; d < 32; ++d)
      s = fmaf(a[h * 64 + d], W[(size_t)(h * 32 + d) * 256 + k], s);
    (cs ? wa_c : wa_d)[i2] = s * L2E;
  }
}

// ======= gemm2: MFMA GEMM [0,768) | et dots [768,1536), 64 threads =======
__global__ __launch_bounds__(64) void gemm2(
    const unsigned short* __restrict__ Xb_c, const unsigned short* __restrict__ Wb_c,
    const unsigned short* __restrict__ Xb_d, const unsigned short* __restrict__ Wb_d,
    const float* __restrict__ c_a, const float* __restrict__ d_a,
    unsigned short* __restrict__ Sbt_c, unsigned short* __restrict__ Sbt_d,
    float* __restrict__ es2t_c, float* __restrict__ es2t_d,
    const float* __restrict__ c_feat, const float* __restrict__ d_feat,
    const float* __restrict__ wa_c, const float* __restrict__ wa_d,
    float* __restrict__ et2_c, float* __restrict__ et2_d) {
  const int b = blockIdx.x;
  if (b < 768) {
    const bool cs = b < 256;
    const int bb = cs ? b : b - 256;
    const int rt = bb >> 1, half = bb & 1;
    const unsigned short* Xb = cs ? Xb_c : Xb_d;
    const unsigned short* Wb = cs ? Wb_c : Wb_d;
    const float* av = cs ? c_a : d_a;
    unsigned short* Sbt = cs ? Sbt_c : Sbt_d;
    float* es2t = cs ? es2t_c : es2t_d;
    const int Mrows = cs ? 2048 : 4096;
    const int l = threadIdx.x;
    const int g = l >> 4, c16 = l & 15;
    bfrag afr[8];
#pragma unroll
    for (int kt = 0; kt < 8; ++kt)
      afr[kt] = *(const bfrag*)(Xb + ((size_t)(rt * 8 + kt) * 64 + l) * 8);
    float esacc[4] = {};
#pragma unroll
    for (int c8 = 0; c8 < 8; ++c8) {
      const int cht = half * 8 + c8;
      f32x4 acc = {0.f, 0.f, 0.f, 0.f};
#pragma unroll
      for (int kt = 0; kt < 8; ++kt) {
        bfrag wfr = *(const bfrag*)(Wb + ((size_t)(cht * 8 + kt) * 64 + l) * 8);
        acc = MFMA16(afr[kt], wfr, acc);
      }
      const int mtb = rt * 2 + (g >> 1);
      size_t soff = (((size_t)cht * (Mrows >> 3) + mtb) * 16 + c16) * 8 + (g & 1) * 4;
      uint2 u;
      u.x = (unsigned)cvtpk(acc[0], acc[1]);
      u.y = (unsigned)cvtpk(acc[2], acc[3]);
      *(uint2*)(Sbt + soff) = u;
      const int h = cht >> 1, sub = cht & 1;
      const float aw = av[h * 64 + 32 + sub * 16 + c16];
      if (sub == 0) {
#pragma unroll
        for (int i = 0; i < 4; ++i) esacc[i] = acc[i] * aw;
      } else {
#pragma unroll
        for (int i = 0; i < 4; ++i) esacc[i] = fmaf(acc[i], aw, esacc[i]);
#pragma unroll
        for (int i = 0; i < 4; ++i) {
          esacc[i] += __shfl_xor(esacc[i], 1);
          esacc[i] += __shfl_xor(esacc[i], 2);
          esacc[i] += __shfl_xor(esacc[i], 4);
          esacc[i] += __shfl_xor(esacc[i], 8);
        }
        if (c16 == 0) {
          f4 o = {esacc[0] * L2E, esacc[1] * L2E, esacc[2] * L2E, esacc[3] * L2E};
          *(f4*)(es2t + (size_t)h * Mrows + rt * 16 + g * 4) = o;
        }
      }
    }
  } else {
    int idx = (b - 768) * 64 + threadIdx.x;   // < 49152
    bool cs = idx < 32768;
    int i2 = cs ? idx : idx - 32768;
    const float* X = cs ? c_feat : d_feat;
    const float* wa = cs ? wa_c : wa_d;
    float* et2 = cs ? et2_c : et2_d;
    int r = i2 >> 3, h = i2 & 7;
    const float* xp = X + (size_t)r * 256;
    const float* ap = wa + h * 256;
    float s = 0.f;
#pragma unroll 16
    for (int k = 0; k < 256; k += 4) {
      f4 xv = *(const f4*)(xp + k);
      f4 av = *(const f4*)(ap + k);
      s = fmaf(xv.x, av.x, s); s = fmaf(xv.y, av.y, s);
      s = fmaf(xv.z, av.z, s); s = fmaf(xv.w, av.w, s);
    }
    et2[i2] = s;
  }
}

// ------- P-gen (exp2, masked AFTER exp2) -------
__device__ __forceinline__ bfrag make_pfrag2(float et, f4 e0, f4 e1,
                                             unsigned bits) {
  float xv[8] = {e0.x, e0.y, e0.z, e0.w, e1.x, e1.y, e1.z, e1.w};
  float p[8];
#pragma unroll
  for (int e = 0; e < 8; ++e) {
    float x = et + xv[e];
    x = fmaxf(x, 0.2f * x);                 // LeakyReLU (exp2 domain)
    float pe = __builtin_amdgcn_exp2f(x);
    p[e] = ((bits >> e) & 1u) ? pe : 0.f;
  }
  union { bfrag v; int i[4]; } u;
#pragma unroll
  for (int e = 0; e < 4; ++e) u.i[e] = cvtpk(p[2 * e], p[2 * e + 1]);
  return u.v;
}

// SWZ=1: (ccc,ccd)=(2,4) XCD-aware mapping, grid 1024.
// CHT: chunk length; inner unroll capped at 8 bodies (512 m) to avoid spill.
template <int FINAL, int SWZ, int CHT>
__global__ __launch_bounds__(256) void fused_attn(
    const float* __restrict__ et2_c, const float* __restrict__ es2t_c,
    const unsigned* __restrict__ adjP, const unsigned short* __restrict__ Sbt_c,
    float* __restrict__ pnum_c, float* __restrict__ pden_c,
    const float* __restrict__ et2_d, const float* __restrict__ es2t_d,
    const unsigned* __restrict__ adjPT, const unsigned short* __restrict__ Sbt_d,
    float* __restrict__ pnum_d, float* __restrict__ pden_d,
    float* __restrict__ out,
    const float* __restrict__ gc, const float* __restrict__ bc,
    const float* __restrict__ gd, const float* __restrict__ bd,
    int NBC, int CH_C, int CH_D) {
  const int b = blockIdx.x;
  bool cs; int chunk, tile;
  if (SWZ) {
    // (2,4): blocks sharing (side, m-chunk) land on dedicated XCD residues:
    // c chunk0 -> xcd{0,1}, c chunk1 -> xcd{2,3}, d chunk j -> xcd 4+j.
    const int r = b & 7;
    if (r < 4) { cs = true;  chunk = r >> 1; tile = (b >> 3) + (r & 1) * 128; }
    else       { cs = false; chunk = r - 4;  tile = b >> 3; }
  } else {
    cs = b < NBC;
    const int bb = cs ? b : b - NBC;
    tile = cs ? (bb & 255) : (bb & 127);
    chunk = cs ? (bb >> 8) : (bb >> 7);
  }
  const int n0 = tile * 16;
  const int M = cs ? 2048 : 4096;
  const int ROWS = cs ? 4096 : 2048;
  const int CH = CHT ? CHT : (cs ? CH_C : CH_D);
  const float* et2 = cs ? et2_c : et2_d;
  const float* es2t = cs ? es2t_c : es2t_d;
  const unsigned* adjPk = cs ? adjP : adjPT;
  const unsigned short* Sbt = cs ? Sbt_c : Sbt_d;
  float* pnum = cs ? pnum_c : pnum_d;
  float* pden = cs ? pden_c : pden_d;
  const float* bng = cs ? gc : gd;
  const float* bnb = cs ? bc : bd;
  float* outp = cs ? out : out + (size_t)4096 * 256;

  const int mstart = chunk * CH;
  const int mend = mstart + CH;
  const int Mw = M >> 5;
  const int tid = threadIdx.x;
  const int w = tid >> 6, l = tid & 63;
  const int g = l >> 4, c16 = l & 15;
  const int hA = w * 2, hB = w * 2 + 1;
  const int row = n0 + c16;
  const float etA = et2[row * 8 + hA];
  const float etB = et2[row * 8 + hB];
  const int Mt16 = M * 16;
  const int lane_off = g * 128 + c16 * 8;
  const unsigned short* pA0 = Sbt + (size_t)(hA * 2) * Mt16 + lane_off;
  const unsigned short* pA1 = pA0 + Mt16;
  const unsigned short* pB0 = Sbt + (size_t)(hB * 2) * Mt16 + lane_off;
  const unsigned short* pB1 = pB0 + Mt16;
  const unsigned* adjt = adjPk + (size_t)tile * Mw * 16 + c16;
  const float* esArow = es2t + (size_t)hA * M;
  const float* esBrow = es2t + (size_t)hB * M;
  f32x4 accA0 = {0.f, 0.f, 0.f, 0.f}, accA1 = accA0, denA = accA0;
  f32x4 accB0 = accA0, accB1 = accA0, denB = accA0;
  union { bfrag v; int i[4]; } uo;
#pragma unroll
  for (int e = 0; e < 4; ++e) uo.i[e] = 0x3F803F80;   // bf16(1.0) pairs
  const bfrag ones = uo.v;

  auto body = [&](int m0) {
    const unsigned w0 = adjt[(m0 >> 5) * 16];
    const unsigned w1 = adjt[(m0 >> 5) * 16 + 16];
    const int moa = m0 + g * 8;
    const int i8 = (m0 >> 3) * 128;
    f4 eA0 = *(const f4*)(esArow + moa);
    f4 eA1 = *(const f4*)(esArow + moa + 4);
    f4 eB0 = *(const f4*)(esBrow + moa);
    f4 eB1 = *(const f4*)(esBrow + moa + 4);
    f4 fA0 = *(const f4*)(esArow + moa + 32);
    f4 fA1 = *(const f4*)(esArow + moa + 36);
    f4 fB0 = *(const f4*)(esBrow + moa + 32);
    f4 fB1 = *(const f4*)(esBrow + moa + 36);
    bfrag bA0a = *(const bfrag*)(pA0 + i8);
    bfrag bA1a = *(const bfrag*)(pA1 + i8);
    bfrag bB0a = *(const bfrag*)(pB0 + i8);
    bfrag bB1a = *(const bfrag*)(pB1 + i8);
    bfrag bA0b = *(const bfrag*)(pA0 + i8 + 512);
    bfrag bA1b = *(const bfrag*)(pA1 + i8 + 512);
    bfrag bB0b = *(const bfrag*)(pB0 + i8 + 512);
    bfrag bB1b = *(const bfrag*)(pB1 + i8 + 512);
    const unsigned bits0 = (w0 >> (g * 8)) & 0xffu;
    const unsigned bits1 = (w1 >> (g * 8)) & 0xffu;
    bfrag aA = make_pfrag2(etA, eA0, eA1, bits0);
    bfrag aB = make_pfrag2(etB, eB0, eB1, bits0);
    __builtin_amdgcn_s_setprio(1);
    accA0 = MFMA16(aA, bA0a, accA0);
    accA1 = MFMA16(aA, bA1a, accA1);
    denA  = MFMA16(aA, ones, denA);
    accB0 = MFMA16(aB, bB0a, accB0);
    accB1 = MFMA16(aB, bB1a, accB1);
    denB  = MFMA16(aB, ones, denB);
    __builtin_amdgcn_s_setprio(0);
    bfrag cA = make_pfrag2(etA, fA0, fA1, bits1);
    bfrag cB = make_pfrag2(etB, fB0, fB1, bits1);
    __builtin_amdgcn_s_setprio(1);
    accA0 = MFMA16(cA, bA0b, accA0);
    accA1 = MFMA16(cA, bA1b, accA1);
    denA  = MFMA16(cA, ones, denA);
    accB0 = MFMA16(cB, bB0b, accB0);
    accB1 = MFMA16(cB, bB1b, accB1);
    denB  = MFMA16(cB, ones, denB);
    __builtin_amdgcn_s_setprio(0);
  };

  if (CHT) {
#pragma unroll 1
    for (int mm = 0; mm < CHT; mm += 512) {
#pragma unroll
      for (int it = 0; it < 8; ++it)
        body(mstart + mm + it * 64);
    }
  } else {
    for (int m0 = mstart; m0 < mend; m0 += 64)
      body(m0);
  }

#define EPILOGUE(acc0, acc1, den, h)                                          \
  {                                                                           \
    const int c0 = (h) * 32 + c16, c1 = (h) * 32 + 16 + c16;                  \
    if (FINAL) {                                                              \
      const float g0 = bng[c0] * BNF, b0 = bnb[c0];                           \
      const float g1 = bng[c1] * BNF, b1 = bnb[c1];                           \
      _Pragma("unroll") for (int i = 0; i < 4; ++i) {                         \
        float rs = 1.f / fmaxf(den[i], 1e-30f);                               \
        float* op = outp + (size_t)(n0 + g * 4 + i) * 256;                    \
        op[c0] = fmaxf(fmaf(acc0[i] * rs, g0, b0), 0.f);                      \
        op[c1] = fmaxf(fmaf(acc1[i] * rs, g1, b1), 0.f);                      \
      }                                                                       \
    } else {                                                                  \
      _Pragma("unroll") for (int i = 0; i < 4; ++i) {                         \
        size_t rr = (size_t)chunk * ROWS + n0 + g * 4 + i;                    \
        pnum[rr * 256 + c0] = acc0[i];                                        \
        pnum[rr * 256 + c1] = acc1[i];                                        \
        if (c16 == 0) pden[rr * 8 + (h)] = den[i];                            \
      }                                                                       \
    }                                                                         \
  }
  EPILOGUE(accA0, accA1, denA, hA)
  EPILOGUE(accB0, accB1, denB, hB)
#undef EPILOGUE
}

// ------- finalize: sum partials, divide, BN, ReLU (both sides) -------
__global__ __launch_bounds__(256) void finalize_k(
    const float* __restrict__ pnum_c, const float* __restrict__ pden_c,
    const float* __restrict__ pnum_d, const float* __restrict__ pden_d,
    float* __restrict__ out,
    const float* __restrict__ gc, const float* __restrict__ bc,
    const float* __restrict__ gd, const float* __restrict__ bd,
    int cc_c, int cc_d) {
  const int b = blockIdx.x;
  const bool cs = b < 1024;
  const int idx = (cs ? b : b - 1024) * 256 + threadIdx.x;
  const int rows = cs ? 4096 : 2048;
  const int cc = cs ? cc_c : cc_d;
  const float* pnum = cs ? pnum_c : pnum_d;
  const float* pden = cs ? pden_c : pden_d;
  const float* bng = cs ? gc : gd;
  const float* bnb = cs ? bc : bd;
  float* outp = cs ? out : out + (size_t)4096 * 256;
  int r = idx >> 6, c4 = (idx & 63) * 4;
  int h = c4 >> 5;
  f4 num = {0.f, 0.f, 0.f, 0.f};
  float den = 0.f;
  for (int c = 0; c < cc; ++c) {
    size_t rr = (size_t)c * rows + r;
    num += __builtin_nontemporal_load((const f4*)(pnum + rr * 256 + c4));
    den += __builtin_nontemporal_load(pden + rr * 8 + h);
  }
  float rs = 1.f / fmaxf(den, 1e-30f);
  f4 gm = *(const f4*)(bng + c4);
  f4 bb = *(const f4*)(bnb + c4);
  f4 o;
  o.x = fmaxf(fmaf(num.x * rs, gm.x * BNF, bb.x), 0.f);
  o.y = fmaxf(fmaf(num.y * rs, gm.y * BNF, bb.y), 0.f);
  o.z = fmaxf(fmaf(num.z * rs, gm.z * BNF, bb.z), 0.f);
  o.w = fmaxf(fmaf(num.w * rs, gm.w * BNF, bb.w), 0.f);
  *(f4*)(outp + (size_t)r * 256 + c4) = o;
}

extern "C" void kernel_launch(void* const* d_in, const int* in_sizes, int n_in,
                              void* d_out, int out_size, void* d_ws, size_t ws_size,
                              hipStream_t stream) {
  const float* c_feat = (const float*)d_in[0];   // [4096,256]
  const float* d_feat = (const float*)d_in[1];   // [2048,256]
  const int*   adj    = (const int*)d_in[2];     // [4096,2048]
  const float* c_W    = (const float*)d_in[3];
  const float* c_a    = (const float*)d_in[4];   // [8,64]
  const float* d_W    = (const float*)d_in[5];
  const float* d_a    = (const float*)d_in[6];
  const float* c_bn_g = (const float*)d_in[7];
  const float* c_bn_b = (const float*)d_in[8];
  const float* d_bn_g = (const float*)d_in[9];
  const float* d_bn_b = (const float*)d_in[10];
  float* out = (float*)d_out;

  char* w = (char*)d_ws;
  size_t off = 0;
  auto take = [&](size_t bytes) -> char* {
    char* p = w + off;
    off += (bytes + 255) & ~(size_t)255;
    return p;
  };
  unsigned short* Sbt_c = (unsigned short*)take(256 * 2048 * 2);
  unsigned short* Sbt_d = (unsigned short*)take(256 * 4096 * 2);
  unsigned short* Xb_c  = (unsigned short*)take(2048 * 256 * 2);
  unsigned short* Xb_d  = (unsigned short*)take(4096 * 256 * 2);
  unsigned short* Wb_c  = (unsigned short*)take(256 * 256 * 2);
  unsigned short* Wb_d  = (unsigned short*)take(256 * 256 * 2);
  float* et2_c  = (float*)take(4096 * 8 * 4);
  float* es2t_c = (float*)take(8 * 2048 * 4);
  float* et2_d  = (float*)take(2048 * 8 * 4);
  float* es2t_d = (float*)take(8 * 4096 * 4);
  float* wa_c   = (float*)take(8 * 256 * 4);
  float* wa_d   = (float*)take(8 * 256 * 4);
  unsigned* adjP  = (unsigned*)take(4096 * 64 * 4);
  unsigned* adjPT = (unsigned*)take(2048 * 128 * 4);

  // chunk-count ladder by available scratch (prefer (2,4): 1 resident pass)
  const size_t base = off;
  const size_t PC = (size_t)4096 * 256 * 4, PD = (size_t)2048 * 256 * 4;
  const size_t DC = 4096 * 8 * 4, DD = 2048 * 8 * 4;
  auto need = [&](int a, int b2) -> size_t {
    return base + (size_t)a * (PC + DC) + (size_t)b2 * (PD + DD) + 4096;
  };
  int ccc = 0, ccd = 0;
  if (ws_size >= need(2, 4))      { ccc = 2; ccd = 4; }
  else if (ws_size >= need(2, 2)) { ccc = 2; ccd = 2; }

  float* pden_c = nullptr; float* pden_d = nullptr;
  float* pnum_c = nullptr; float* pnum_d = nullptr;
  if (ccc) {
    pden_c = (float*)take((size_t)ccc * DC);
    pden_d = (float*)take((size_t)ccd * DD);
    pnum_c = (float*)take((size_t)ccc * PC);
    pnum_d = (float*)take((size_t)ccd * PD);
  }

  dim3 blk(256);
  prep1<<<2896, blk, 0, stream>>>(c_feat, d_feat, c_W, d_W, c_a, d_a, adj,
                                  adjP, adjPT, Xb_c, Xb_d, Wb_c, Wb_d,
                                  wa_c, wa_d);
  gemm2<<<1536, dim3(64), 0, stream>>>(Xb_c, Wb_c, Xb_d, Wb_d, c_a, d_a,
                                       Sbt_c, Sbt_d, es2t_c, es2t_d,
                                       c_feat, d_feat, wa_c, wa_d,
                                       et2_c, et2_d);

  if (ccc == 2 && ccd == 4) {
    fused_attn<0, 1, 1024><<<1024, blk, 0, stream>>>(
        et2_c, es2t_c, adjP, Sbt_c, pnum_c, pden_c,
        et2_d, es2t_d, adjPT, Sbt_d, pnum_d, pden_d,
        nullptr, c_bn_g, c_bn_b, d_bn_g, d_bn_b,
        512, 1024, 1024);
    finalize_k<<<1536, blk, 0, stream>>>(pnum_c, pden_c, pnum_d, pden_d, out,
                                         c_bn_g, c_bn_b, d_bn_g, d_bn_b, ccc, ccd);
  } else if (ccc) {
    fused_attn<0, 0, 0><<<256 * ccc + 128 * ccd, blk, 0, stream>>>(
        et2_c, es2t_c, adjP, Sbt_c, pnum_c, pden_c,
        et2_d, es2t_d, adjPT, Sbt_d, pnum_d, pden_d,
        nullptr, c_bn_g, c_bn_b, d_bn_g, d_bn_b,
        256 * ccc, 2048 / ccc, 4096 / ccd);
    finalize_k<<<1536, blk, 0, stream>>>(pnum_c, pden_c, pnum_d, pden_d, out,
                                         c_bn_g, c_bn_b, d_bn_g, d_bn_b, ccc, ccd);
  } else {
    fused_attn<1, 0, 0><<<384, blk, 0, stream>>>(
        et2_c, es2t_c, adjP, Sbt_c, nullptr, nullptr,
        et2_d, es2t_d, adjPT, Sbt_d, nullptr, nullptr,
        out, c_bn_g, c_bn_b, d_bn_g, d_bn_b, 256, 2048, 4096);
  }
}